// Round 10
// baseline (86.046 us; speedup 1.0000x reference)
//
#include <hip/hip_runtime.h>
#include <hip/hip_bf16.h>

#define NB 16
#define NN 256
#define NH 8
#define ND 64
#define NT 5
#define HD 512   // NH*ND

typedef __bf16 bf16x8 __attribute__((ext_vector_type(8)));
typedef __bf16 bf16x4 __attribute__((ext_vector_type(4)));
typedef float  f32x4  __attribute__((ext_vector_type(4)));
typedef int    i32x4  __attribute__((ext_vector_type(4)));

__device__ __forceinline__ f32x4 ld4(const float* p) {
    return *reinterpret_cast<const f32x4*>(p);
}

__device__ __forceinline__ bf16x8 cvt8(f32x4 a, f32x4 b) {
    bf16x8 r;
    r[0] = (__bf16)a[0]; r[1] = (__bf16)a[1]; r[2] = (__bf16)a[2]; r[3] = (__bf16)a[3];
    r[4] = (__bf16)b[0]; r[5] = (__bf16)b[1]; r[6] = (__bf16)b[2]; r[7] = (__bf16)b[3];
    return r;
}

// Transpose a[(h*64+dd)*64*5 + e*5 + t] (fp32) -> wt[h][t][e][dd] (bf16).
__global__ void prep_w_kernel(const float* __restrict__ a, __bf16* __restrict__ wt) {
    int idx = blockIdx.x * 256 + threadIdx.x;
    if (idx >= NH * ND * ND * NT) return;
    int t  = idx % NT;
    int e  = (idx / NT) % ND;
    int dd = (idx / (NT * ND)) % ND;
    int h  = idx / (NT * ND * ND);
    wt[(((h * NT + t) * ND + e) * ND) + dd] = (__bf16)a[idx];
}

// ---------------- k1: T[b,h,t,i,e] = sum_dd src[b,i,h,dd] * W[h,dd,e,t] ----------------
// One wave per (b,h,it,t). 12 loads -> ILP fence -> 8 MFMA -> 4 stores.
__global__ __launch_bounds__(64, 4) void k1_transform(
    const float* __restrict__ src, const __bf16* __restrict__ wt,
    __bf16* __restrict__ T)
{
    const int bid = blockIdx.x;
    const int wg  = (bid & 7) * 1280 + (bid >> 3);  // XCD-chunked, bijective (10240=8*1280)
    const int t   = wg % NT;
    const int u   = wg / NT;       // 0..2047, b-major within each XCD chunk
    const int it  = u & 15;
    const int h   = (u >> 4) & 7;
    const int b   = u >> 7;
    const int i0  = it * 16;

    const int l  = threadIdx.x & 63;
    const int il = l & 15;
    const int kg = l >> 4;

    // ---- issue all 12 independent loads ----
    const float* sbase = src + (size_t)(b * NN + i0 + il) * HD + h * ND;
    f32x4 s0 = ld4(sbase + kg * 8);
    f32x4 s1 = ld4(sbase + kg * 8 + 4);
    f32x4 s2 = ld4(sbase + 32 + kg * 8);
    f32x4 s3 = ld4(sbase + 32 + kg * 8 + 4);

    bf16x8 w0[4], w1[4];
    #pragma unroll
    for (int et = 0; et < 4; ++et) {
        const __bf16* wp = wt + (((h * NT + t) * ND + et * 16 + il) * ND) + kg * 8;
        w0[et] = *reinterpret_cast<const bf16x8*>(wp);
        w1[et] = *reinterpret_cast<const bf16x8*>(wp + 32);
    }

    // ---- ILP fence: force all loads live simultaneously (defeat sched sinking) ----
    asm volatile("" : "+v"(s0), "+v"(s1), "+v"(s2), "+v"(s3),
                      "+v"(w0[0]), "+v"(w1[0]), "+v"(w0[1]), "+v"(w1[1]),
                      "+v"(w0[2]), "+v"(w1[2]), "+v"(w0[3]), "+v"(w1[3]));

    bf16x8 af0 = cvt8(s0, s1);
    bf16x8 af1 = cvt8(s2, s3);

    __bf16* tb = T + ((size_t)((b * NH + h) * NT + t) * NN + i0 + il) * ND;
    #pragma unroll
    for (int et = 0; et < 4; ++et) {
        // A = W^T rows (m=e), B = src (n=i): D lane holds e=et*16+kg*4+r, i=il
        f32x4 pacc = {0.f, 0.f, 0.f, 0.f};
        pacc = __builtin_amdgcn_mfma_f32_16x16x32_bf16(w0[et], af0, pacc, 0, 0, 0);
        pacc = __builtin_amdgcn_mfma_f32_16x16x32_bf16(w1[et], af1, pacc, 0, 0, 0);
        bf16x4 pk;
        pk[0] = (__bf16)pacc[0];
        pk[1] = (__bf16)pacc[1];
        pk[2] = (__bf16)pacc[2];
        pk[3] = (__bf16)pacc[3];
        *reinterpret_cast<bf16x4*>(tb + et * 16 + kg * 4) = pk;
    }
}

// ---------------- k2: S[i,j] = select_t( T_t[i,:] . dst[j,:] ), mask, leaky ----------------
// One wave per (16i x 16j) tile. 15 loads -> ILP fence -> 10 MFMA -> 1 store.
__global__ __launch_bounds__(256, 4) void k2_scores(
    const __bf16* __restrict__ T, const float* __restrict__ dst,
    const int* __restrict__ edges, float* __restrict__ out)
{
    const int bid = blockIdx.x;
    const int wg  = (bid & 7) * 1024 + (bid >> 3);  // XCD-chunked, bijective (8192=8*1024)
    const int b   = wg >> 9;
    const int rem = wg & 511;
    const int h   = rem >> 6;          // 0..7
    const int it  = (rem >> 2) & 15;   // 0..15
    const int jg  = rem & 3;           // 0..3
    const int i0  = it * 16;

    const int tid = threadIdx.x;
    const int w   = tid >> 6;
    const int l   = tid & 63;
    const int il  = l & 15;
    const int kg  = l >> 4;
    const int j0  = (jg * 4 + w) * 16;

    // ---- issue all 15 independent loads ----
    const float* dp = dst + (size_t)b * NN * HD + h * ND + (size_t)(j0 + il) * HD + kg * 8;
    f32x4 q0 = ld4(dp);
    f32x4 q1 = ld4(dp + 4);
    f32x4 q2 = ld4(dp + 32);
    f32x4 q3 = ld4(dp + 36);

    i32x4 ce = *reinterpret_cast<const i32x4*>(
        edges + ((size_t)b * NN + i0 + il) * NN + j0 + kg * 4);

    const __bf16* Tb = T + (size_t)((b * NH + h) * NT) * NN * ND + (i0 + il) * ND;
    bf16x8 pa[NT][2];
    #pragma unroll
    for (int t = 0; t < NT; ++t) {
        #pragma unroll
        for (int ks = 0; ks < 2; ++ks) {
            pa[t][ks] = *reinterpret_cast<const bf16x8*>(
                Tb + (size_t)t * NN * ND + ks * 32 + kg * 8);
        }
    }

    // ---- ILP fence: all 15 loads must be live here -> parallel issue, one waitcnt ----
    asm volatile("" : "+v"(q0), "+v"(q1), "+v"(q2), "+v"(q3), "+v"(ce),
                      "+v"(pa[0][0]), "+v"(pa[0][1]), "+v"(pa[1][0]), "+v"(pa[1][1]),
                      "+v"(pa[2][0]), "+v"(pa[2][1]), "+v"(pa[3][0]), "+v"(pa[3][1]),
                      "+v"(pa[4][0]), "+v"(pa[4][1]));

    // ---- compute ----
    const bf16x8 cb0 = cvt8(q0, q1);
    const bf16x8 cb1 = cvt8(q2, q3);

    f32x4 acc[NT];
    #pragma unroll
    for (int t = 0; t < NT; ++t) {
        acc[t] = (f32x4){0.f, 0.f, 0.f, 0.f};
        // A = dst rows (m=j), B = T (n=i): D lane holds j=kg*4+r, i=il
        acc[t] = __builtin_amdgcn_mfma_f32_16x16x32_bf16(cb0, pa[t][0], acc[t], 0, 0, 0);
        acc[t] = __builtin_amdgcn_mfma_f32_16x16x32_bf16(cb1, pa[t][1], acc[t], 0, 0, 0);
    }

    f32x4 o;
    #pragma unroll
    for (int r = 0; r < 4; ++r) {
        const int ev = ce[r];
        float x;
        if (ev < 0) { x = -1e10f; }
        else {
            x = (ev == 0) ? acc[0][r]
              : (ev == 1) ? acc[1][r]
              : (ev == 2) ? acc[2][r]
              : (ev == 3) ? acc[3][r]
              :             acc[4][r];
        }
        o[r] = (x >= 0.f) ? x : 0.2f * x;
    }
    *reinterpret_cast<f32x4*>(
        out + ((size_t)(b * NH + h) * NN + i0 + il) * NN + j0 + kg * 4) = o;
}

// ---------------- fallback (ws too small): fused 1-wave kernel, araw path ----------------
__global__ __launch_bounds__(64, 3) void mhea_fused_fallback(
    const float* __restrict__ src, const float* __restrict__ dst,
    const float* __restrict__ araw, const int* __restrict__ edges,
    float* __restrict__ out)
{
    __shared__ __bf16 Plds[NT * 16 * 64];

    const int it = blockIdx.x;
    const int h  = blockIdx.y;
    const int b  = blockIdx.z;
    const int i0 = it * 16;

    const int l  = threadIdx.x & 63;
    const int il = l & 15;
    const int kg = l >> 4;

    const float* dbase = dst + (size_t)b * NN * HD + h * ND;
    const int*   erow  = edges + ((size_t)b * NN + i0 + il) * NN;
    const float* sbase = src + (size_t)(b * NN + i0 + il) * HD + h * ND;

    f32x4 s0 = ld4(sbase + kg * 8);
    f32x4 s1 = ld4(sbase + kg * 8 + 4);
    f32x4 s2 = ld4(sbase + 32 + kg * 8);
    f32x4 s3 = ld4(sbase + 32 + kg * 8 + 4);
    bf16x8 af0 = cvt8(s0, s1);
    bf16x8 af1 = cvt8(s2, s3);

    #pragma unroll
    for (int t = 0; t < NT; ++t) {
        #pragma unroll
        for (int et = 0; et < 4; ++et) {
            bf16x8 w0, w1;
            #pragma unroll
            for (int jj = 0; jj < 8; ++jj) {
                const int e = et * 16 + il;
                w0[jj] = (__bf16)araw[((size_t)(h * ND + kg * 8 + jj) * ND + e) * NT + t];
                w1[jj] = (__bf16)araw[((size_t)(h * ND + kg * 8 + jj + 32) * ND + e) * NT + t];
            }
            f32x4 pacc = {0.f, 0.f, 0.f, 0.f};
            pacc = __builtin_amdgcn_mfma_f32_16x16x32_bf16(w0, af0, pacc, 0, 0, 0);
            pacc = __builtin_amdgcn_mfma_f32_16x16x32_bf16(w1, af1, pacc, 0, 0, 0);
            bf16x4 pk;
            pk[0] = (__bf16)pacc[0];
            pk[1] = (__bf16)pacc[1];
            pk[2] = (__bf16)pacc[2];
            pk[3] = (__bf16)pacc[3];
            const int elem = (et * 16 + kg * 4) ^ ((il & 7) << 3);
            *reinterpret_cast<bf16x4*>(&Plds[t * 1024 + il * 64 + elem]) = pk;
        }
    }

    bf16x8 pa[NT][2];
    #pragma unroll
    for (int t = 0; t < NT; ++t) {
        #pragma unroll
        for (int ks = 0; ks < 2; ++ks) {
            const int elem = (ks * 32 + kg * 8) ^ ((il & 7) << 3);
            pa[t][ks] = *reinterpret_cast<const bf16x8*>(&Plds[t * 1024 + il * 64 + elem]);
        }
    }

    float* obase = out + (((size_t)(b * NH + h)) * NN + i0 + il) * NN;

    for (int jt = 0; jt < 16; ++jt) {
        const float* np = dbase + (size_t)(jt * 16 + il) * HD + kg * 8;
        f32x4 d0 = ld4(np), d1 = ld4(np + 4), d2 = ld4(np + 32), d3 = ld4(np + 36);
        i32x4 ce = *reinterpret_cast<const i32x4*>(erow + jt * 16 + kg * 4);
        const bf16x8 cb0 = cvt8(d0, d1);
        const bf16x8 cb1 = cvt8(d2, d3);
        f32x4 acc[NT];
        #pragma unroll
        for (int t = 0; t < NT; ++t) {
            acc[t] = (f32x4){0.f, 0.f, 0.f, 0.f};
            acc[t] = __builtin_amdgcn_mfma_f32_16x16x32_bf16(cb0, pa[t][0], acc[t], 0, 0, 0);
            acc[t] = __builtin_amdgcn_mfma_f32_16x16x32_bf16(cb1, pa[t][1], acc[t], 0, 0, 0);
        }
        f32x4 o;
        #pragma unroll
        for (int r = 0; r < 4; ++r) {
            const int ev = ce[r];
            float x;
            if (ev < 0) { x = -1e10f; }
            else {
                x = (ev == 0) ? acc[0][r]
                  : (ev == 1) ? acc[1][r]
                  : (ev == 2) ? acc[2][r]
                  : (ev == 3) ? acc[3][r]
                  :             acc[4][r];
            }
            o[r] = (x >= 0.f) ? x : 0.2f * x;
        }
        *reinterpret_cast<f32x4*>(obase + jt * 16 + kg * 4) = o;
    }
}

extern "C" void kernel_launch(void* const* d_in, const int* in_sizes, int n_in,
                              void* d_out, int out_size, void* d_ws, size_t ws_size,
                              hipStream_t stream) {
    const float* src   = (const float*)d_in[0];
    const float* dst   = (const float*)d_in[1];
    const float* a     = (const float*)d_in[2];
    const int*   edges = (const int*)d_in[3];
    float* out = (float*)d_out;

    const size_t wt_bytes = (size_t)NH * NT * ND * ND * sizeof(__bf16);  // 320 KB
    const size_t t_off    = 1 << 20;                                     // 1 MB align
    const size_t t_bytes  = (size_t)NB * NH * NT * NN * ND * sizeof(__bf16);  // 21 MB

    if (ws_size >= t_off + t_bytes && wt_bytes <= t_off) {
        __bf16* wt = (__bf16*)d_ws;
        __bf16* T  = (__bf16*)((char*)d_ws + t_off);
        const int total = NH * ND * ND * NT;
        prep_w_kernel<<<(total + 255) / 256, 256, 0, stream>>>(a, wt);
        k1_transform<<<10240, 64, 0, stream>>>(src, wt, T);
        k2_scores<<<8192, 256, 0, stream>>>(T, dst, edges, out);
    } else {
        mhea_fused_fallback<<<dim3(NN / 16, NH, NB), 64, 0, stream>>>(
            src, dst, a, edges, out);
    }
}

// Round 12
// 38.289 us; speedup vs baseline: 2.2473x; 2.2473x over previous
//
#include <hip/hip_runtime.h>
#include <hip/hip_bf16.h>

#define NB 16
#define NN 256
#define NH 8
#define ND 64
#define NT 5
#define HD 512   // NH*ND

typedef __bf16 bf16x8 __attribute__((ext_vector_type(8)));
typedef __bf16 bf16x4 __attribute__((ext_vector_type(4)));
typedef float  f32x4  __attribute__((ext_vector_type(4)));
typedef int    i32x4  __attribute__((ext_vector_type(4)));

__device__ __forceinline__ bf16x8 cvt8(f32x4 a, f32x4 b) {
    bf16x8 r;
    r[0] = (__bf16)a[0]; r[1] = (__bf16)a[1]; r[2] = (__bf16)a[2]; r[3] = (__bf16)a[3];
    r[4] = (__bf16)b[0]; r[5] = (__bf16)b[1]; r[6] = (__bf16)b[2]; r[7] = (__bf16)b[3];
    return r;
}

// fire-and-forget global->LDS: lane l writes LDS[base + l*16]; src addr is per-lane.
__device__ __forceinline__ void stage16(const void* g, void* l) {
    __builtin_amdgcn_global_load_lds(
        (const __attribute__((address_space(1))) void*)g,
        (__attribute__((address_space(3))) void*)l,
        16, 0, 0);
}

// Transpose a[(h*64+dd)*64*5 + e*5 + t] (fp32) -> wt[h][t][e][dd] (bf16).
__global__ void prep_w_kernel(const float* __restrict__ a, __bf16* __restrict__ wt) {
    int idx = blockIdx.x * 256 + threadIdx.x;
    if (idx >= NH * ND * ND * NT) return;
    int t  = idx % NT;
    int e  = (idx / NT) % ND;
    int dd = (idx / (NT * ND)) % ND;
    int h  = idx / (NT * ND * ND);
    wt[(((h * NT + t) * ND + e) * ND) + dd] = (__bf16)a[idx];
}

// ================= k1: T[b,h,t,i,e] = sum_dd src[b,i,h,dd] * W[h,dd,e,t] =================
// Block = (b,h,t,i-half). All inputs staged to LDS by DMA; compute is LDS+MFMA only.
__global__ __launch_bounds__(256, 4) void k1_transform(
    const float* __restrict__ src, const __bf16* __restrict__ wt,
    __bf16* __restrict__ T)
{
    // W: rows e(64) x 128B, 16B-chunk c holds global chunk c^(e&7)     (8 KB)
    __shared__ alignas(16) __bf16 Wl[ND * ND];
    // S: rows i(128) x 256B, 16B-chunk c holds global chunk c^(i&7)    (32 KB)
    __shared__ alignas(16) float  Sl[128 * ND];

    const int bid = blockIdx.x;
    const int wg  = (bid & 7) * 160 + (bid >> 3);   // bijective, 1280 = 8*160
    const int t   = wg % NT;
    const int u   = wg / NT;      // 0..255
    const int ih  = u & 1;
    const int h   = (u >> 1) & 7;
    const int b   = u >> 4;

    const int tid = threadIdx.x;
    const int w   = tid >> 6;
    const int l   = tid & 63;
    const int il  = l & 15;
    const int kg  = l >> 4;

    // ---- DMA staging (pre-swizzled source, linear LDS dest) ----
    const __bf16* wgp = wt + (size_t)((h * NT + t) * ND) * ND;
    #pragma unroll
    for (int k = 0; k < 2; ++k) {            // W: 8 x 1KB
        const int idx = w * 2 + k;
        const int e   = idx * 8 + (l >> 3);
        const int c   = (l & 7) ^ (e & 7);
        stage16(wgp + (size_t)e * ND + c * 8, &Wl[idx * 8 * ND]);
    }
    #pragma unroll
    for (int k = 0; k < 8; ++k) {            // S: 32 x 1KB
        const int idx = w * 8 + k;
        const int ii  = idx * 4 + (l >> 4);
        const int c   = (l & 15) ^ (ii & 7);
        stage16(src + ((size_t)(b * NN + ih * 128 + ii)) * HD + h * ND + c * 4,
                &Sl[idx * 4 * ND]);
    }

    __syncthreads();   // vmcnt(0) drain = staging fence

    // A-frags (W rows, e = et*16+il, k-elems ks*32+kg*8..+7)
    bf16x8 af[4][2];
    #pragma unroll
    for (int et = 0; et < 4; ++et)
        #pragma unroll
        for (int ks = 0; ks < 2; ++ks)
            af[et][ks] = *reinterpret_cast<const bf16x8*>(
                &Wl[(et * 16 + il) * ND + (((ks * 4 + kg) ^ (il & 7)) << 3)]);

    #pragma unroll
    for (int it2 = 0; it2 < 2; ++it2) {
        const int iloc = (w * 2 + it2) * 16 + il;
        f32x4 f00 = *reinterpret_cast<const f32x4*>(&Sl[iloc * ND + (((2 * kg + 0) ^ (il & 7)) << 2)]);
        f32x4 f01 = *reinterpret_cast<const f32x4*>(&Sl[iloc * ND + (((2 * kg + 1) ^ (il & 7)) << 2)]);
        f32x4 f10 = *reinterpret_cast<const f32x4*>(&Sl[iloc * ND + (((8 + 2 * kg) ^ (il & 7)) << 2)]);
        f32x4 f11 = *reinterpret_cast<const f32x4*>(&Sl[iloc * ND + (((9 + 2 * kg) ^ (il & 7)) << 2)]);
        bf16x8 bf0 = cvt8(f00, f01);
        bf16x8 bf1 = cvt8(f10, f11);

        __bf16* tb = T + (((size_t)(b * NH + h) * NT + t) * NN + ih * 128 + iloc) * ND;
        #pragma unroll
        for (int et = 0; et < 4; ++et) {
            // A = W^T rows (m=e), B = src (n=i): lane holds e=et*16+kg*4+r, i=il
            f32x4 pacc = {0.f, 0.f, 0.f, 0.f};
            pacc = __builtin_amdgcn_mfma_f32_16x16x32_bf16(af[et][0], bf0, pacc, 0, 0, 0);
            pacc = __builtin_amdgcn_mfma_f32_16x16x32_bf16(af[et][1], bf1, pacc, 0, 0, 0);
            bf16x4 pk;
            pk[0] = (__bf16)pacc[0];
            pk[1] = (__bf16)pacc[1];
            pk[2] = (__bf16)pacc[2];
            pk[3] = (__bf16)pacc[3];
            *reinterpret_cast<bf16x4*>(tb + et * 16 + kg * 4) = pk;
        }
    }
}

// ================= k2: S[i,j] = leaky(mask(select_t(T_t[i,:] . dst[j,:]))) =================
// Block = (b,h,16i,128j). T/dst/edges all staged by DMA; post-barrier is pure LDS+MFMA.
__global__ __launch_bounds__(256, 3) void k2_scores(
    const __bf16* __restrict__ T, const float* __restrict__ dst,
    const int* __restrict__ edges, float* __restrict__ out)
{
    // T: rows (t*16+i)(80) x 128B, chunk c holds global c^(row&7)      (10 KB)
    __shared__ alignas(16) __bf16 Tl[NT * 16 * ND];
    // D: rows j(128) x 256B, chunk c holds global c^(j&7)              (32 KB)
    __shared__ alignas(16) float  Dl[128 * ND];
    // E: rows i(16) x 512B, chunk c holds global c^(i&7)               (8 KB)
    __shared__ alignas(16) int    El[16 * 128];

    const int bid = blockIdx.x;
    const int wg  = (bid & 7) * 512 + (bid >> 3);   // bijective, 4096 = 8*512
    const int b   = wg >> 8;
    const int rem = wg & 255;
    const int h   = rem >> 5;
    const int rm2 = rem & 31;
    const int it  = rm2 >> 1;
    const int jh  = rm2 & 1;
    const int i0  = it * 16;
    const int j0  = jh * 128;

    const int tid = threadIdx.x;
    const int w   = tid >> 6;
    const int l   = tid & 63;
    const int il  = l & 15;
    const int kg  = l >> 4;

    // ---- DMA staging ----
    const __bf16* Tg = T + ((size_t)(b * NH + h) * NT) * NN * ND;
    #pragma unroll
    for (int k = 0; k < 3; ++k) {            // T: 10 x 1KB
        const int idx = k * 4 + w;
        if (idx < 10) {
            const int rloc = idx * 8 + (l >> 3);     // row = t*16 + iloc
            const int tt   = rloc >> 4;
            const int iloc = rloc & 15;
            const int c    = (l & 7) ^ (rloc & 7);
            stage16(Tg + ((size_t)tt * NN + i0 + iloc) * ND + c * 8, &Tl[idx * 8 * ND]);
        }
    }
    #pragma unroll
    for (int k = 0; k < 8; ++k) {            // D: 32 x 1KB
        const int idx  = w * 8 + k;
        const int jloc = idx * 4 + (l >> 4);
        const int c    = (l & 15) ^ (jloc & 7);
        stage16(dst + ((size_t)(b * NN + j0 + jloc)) * HD + h * ND + c * 4,
                &Dl[idx * 4 * ND]);
    }
    #pragma unroll
    for (int k = 0; k < 2; ++k) {            // E: 8 x 1KB
        const int idx  = w * 2 + k;
        const int iloc = idx * 2 + (l >> 5);
        const int c    = (l & 31) ^ (iloc & 7);
        stage16(edges + ((size_t)(b * NN + i0 + iloc)) * NN + j0 + c * 4,
                &El[idx * 2 * 128]);
    }

    __syncthreads();   // vmcnt(0) drain = staging fence

    // B-frags: T row i=il, k-elems ks*32+kg*8..+7
    bf16x8 pa[NT][2];
    #pragma unroll
    for (int t = 0; t < NT; ++t)
        #pragma unroll
        for (int ks = 0; ks < 2; ++ks)
            pa[t][ks] = *reinterpret_cast<const bf16x8*>(
                &Tl[(t * 16 + il) * ND + (((ks * 4 + kg) ^ (il & 7)) << 3)]);

    float* obase = out + ((size_t)(b * NH + h) * NN + i0 + il) * NN + j0;

    #pragma unroll
    for (int jt2 = 0; jt2 < 2; ++jt2) {
        const int jt   = w * 2 + jt2;        // local j-tile 0..7
        const int jrow = jt * 16 + il;
        f32x4 q0 = *reinterpret_cast<const f32x4*>(&Dl[jrow * ND + (((2 * kg + 0) ^ (il & 7)) << 2)]);
        f32x4 q1 = *reinterpret_cast<const f32x4*>(&Dl[jrow * ND + (((2 * kg + 1) ^ (il & 7)) << 2)]);
        f32x4 q2 = *reinterpret_cast<const f32x4*>(&Dl[jrow * ND + (((8 + 2 * kg) ^ (il & 7)) << 2)]);
        f32x4 q3 = *reinterpret_cast<const f32x4*>(&Dl[jrow * ND + (((9 + 2 * kg) ^ (il & 7)) << 2)]);
        const bf16x8 cb0 = cvt8(q0, q1);
        const bf16x8 cb1 = cvt8(q2, q3);
        const i32x4 ce = *reinterpret_cast<const i32x4*>(
            &El[il * 128 + (((jt * 4 + kg) ^ (il & 7)) << 2)]);

        f32x4 acc[NT];
        #pragma unroll
        for (int t = 0; t < NT; ++t) {
            acc[t] = (f32x4){0.f, 0.f, 0.f, 0.f};
            // A = dst rows (m=j), B = T (n=i): lane holds j=kg*4+r, i=il
            acc[t] = __builtin_amdgcn_mfma_f32_16x16x32_bf16(cb0, pa[t][0], acc[t], 0, 0, 0);
            acc[t] = __builtin_amdgcn_mfma_f32_16x16x32_bf16(cb1, pa[t][1], acc[t], 0, 0, 0);
        }

        f32x4 o;
        #pragma unroll
        for (int r = 0; r < 4; ++r) {
            const int ev = ce[r];
            float x;
            if (ev < 0) { x = -1e10f; }
            else {
                x = (ev == 0) ? acc[0][r]
                  : (ev == 1) ? acc[1][r]
                  : (ev == 2) ? acc[2][r]
                  : (ev == 3) ? acc[3][r]
                  :             acc[4][r];
            }
            o[r] = (x >= 0.f) ? x : 0.2f * x;
        }
        *reinterpret_cast<f32x4*>(obase + jt * 16 + kg * 4) = o;
    }
}

// ---------------- fallback (ws too small): fused 1-wave kernel, araw path ----------------
__global__ __launch_bounds__(64, 3) void mhea_fused_fallback(
    const float* __restrict__ src, const float* __restrict__ dst,
    const float* __restrict__ araw, const int* __restrict__ edges,
    float* __restrict__ out)
{
    __shared__ __bf16 Plds[NT * 16 * 64];

    const int it = blockIdx.x;
    const int h  = blockIdx.y;
    const int b  = blockIdx.z;
    const int i0 = it * 16;

    const int l  = threadIdx.x & 63;
    const int il = l & 15;
    const int kg = l >> 4;

    const float* dbase = dst + (size_t)b * NN * HD + h * ND;
    const int*   erow  = edges + ((size_t)b * NN + i0 + il) * NN;
    const float* sbase = src + (size_t)(b * NN + i0 + il) * HD + h * ND;

    f32x4 s0 = *reinterpret_cast<const f32x4*>(sbase + kg * 8);
    f32x4 s1 = *reinterpret_cast<const f32x4*>(sbase + kg * 8 + 4);
    f32x4 s2 = *reinterpret_cast<const f32x4*>(sbase + 32 + kg * 8);
    f32x4 s3 = *reinterpret_cast<const f32x4*>(sbase + 36 + kg * 8);
    bf16x8 af0 = cvt8(s0, s1);
    bf16x8 af1 = cvt8(s2, s3);

    #pragma unroll
    for (int t = 0; t < NT; ++t) {
        #pragma unroll
        for (int et = 0; et < 4; ++et) {
            bf16x8 w0, w1;
            #pragma unroll
            for (int jj = 0; jj < 8; ++jj) {
                const int ee = et * 16 + il;
                w0[jj] = (__bf16)araw[((size_t)(h * ND + kg * 8 + jj) * ND + ee) * NT + t];
                w1[jj] = (__bf16)araw[((size_t)(h * ND + kg * 8 + jj + 32) * ND + ee) * NT + t];
            }
            f32x4 pacc = {0.f, 0.f, 0.f, 0.f};
            pacc = __builtin_amdgcn_mfma_f32_16x16x32_bf16(w0, af0, pacc, 0, 0, 0);
            pacc = __builtin_amdgcn_mfma_f32_16x16x32_bf16(w1, af1, pacc, 0, 0, 0);
            bf16x4 pk;
            pk[0] = (__bf16)pacc[0];
            pk[1] = (__bf16)pacc[1];
            pk[2] = (__bf16)pacc[2];
            pk[3] = (__bf16)pacc[3];
            const int elem = (et * 16 + kg * 4) ^ ((il & 7) << 3);
            *reinterpret_cast<bf16x4*>(&Plds[t * 1024 + il * 64 + elem]) = pk;
        }
    }

    bf16x8 pa[NT][2];
    #pragma unroll
    for (int t = 0; t < NT; ++t) {
        #pragma unroll
        for (int ks = 0; ks < 2; ++ks) {
            const int elem = (ks * 32 + kg * 8) ^ ((il & 7) << 3);
            pa[t][ks] = *reinterpret_cast<const bf16x8*>(&Plds[t * 1024 + il * 64 + elem]);
        }
    }

    float* obase = out + (((size_t)(b * NH + h)) * NN + i0 + il) * NN;

    for (int jt = 0; jt < 16; ++jt) {
        const float* np = dbase + (size_t)(jt * 16 + il) * HD + kg * 8;
        f32x4 d0 = *reinterpret_cast<const f32x4*>(np);
        f32x4 d1 = *reinterpret_cast<const f32x4*>(np + 4);
        f32x4 d2 = *reinterpret_cast<const f32x4*>(np + 32);
        f32x4 d3 = *reinterpret_cast<const f32x4*>(np + 36);
        i32x4 ce = *reinterpret_cast<const i32x4*>(erow + jt * 16 + kg * 4);
        const bf16x8 cb0 = cvt8(d0, d1);
        const bf16x8 cb1 = cvt8(d2, d3);
        f32x4 acc[NT];
        #pragma unroll
        for (int t = 0; t < NT; ++t) {
            acc[t] = (f32x4){0.f, 0.f, 0.f, 0.f};
            acc[t] = __builtin_amdgcn_mfma_f32_16x16x32_bf16(cb0, pa[t][0], acc[t], 0, 0, 0);
            acc[t] = __builtin_amdgcn_mfma_f32_16x16x32_bf16(cb1, pa[t][1], acc[t], 0, 0, 0);
        }
        f32x4 o;
        #pragma unroll
        for (int r = 0; r < 4; ++r) {
            const int ev = ce[r];
            float x;
            if (ev < 0) { x = -1e10f; }
            else {
                x = (ev == 0) ? acc[0][r]
                  : (ev == 1) ? acc[1][r]
                  : (ev == 2) ? acc[2][r]
                  : (ev == 3) ? acc[3][r]
                  :             acc[4][r];
            }
            o[r] = (x >= 0.f) ? x : 0.2f * x;
        }
        *reinterpret_cast<f32x4*>(obase + jt * 16 + kg * 4) = o;
    }
}

extern "C" void kernel_launch(void* const* d_in, const int* in_sizes, int n_in,
                              void* d_out, int out_size, void* d_ws, size_t ws_size,
                              hipStream_t stream) {
    const float* src   = (const float*)d_in[0];
    const float* dst   = (const float*)d_in[1];
    const float* a     = (const float*)d_in[2];
    const int*   edges = (const int*)d_in[3];
    float* out = (float*)d_out;

    const size_t wt_bytes = (size_t)NH * NT * ND * ND * sizeof(__bf16);       // 320 KB
    const size_t t_off    = 1 << 20;                                          // 1 MB
    const size_t t_bytes  = (size_t)NB * NH * NT * NN * ND * sizeof(__bf16);  // 21 MB

    if (ws_size >= t_off + t_bytes && wt_bytes <= t_off) {
        __bf16* wt = (__bf16*)d_ws;
        __bf16* T  = (__bf16*)((char*)d_ws + t_off);
        const int total = NH * ND * ND * NT;
        prep_w_kernel<<<(total + 255) / 256, 256, 0, stream>>>(a, wt);
        k1_transform<<<1280, 256, 0, stream>>>(src, wt, T);
        k2_scores<<<4096, 256, 0, stream>>>(T, dst, edges, out);
    } else {
        mhea_fused_fallback<<<dim3(NN / 16, NH, NB), 64, 0, stream>>>(
            src, dst, a, edges, out);
    }
}